// Round 2
// baseline (368.152 us; speedup 1.0000x reference)
//
#include <hip/hip_runtime.h>
#include <hip/hip_bf16.h>

// ActorNetwork fused pipeline for MI355X — round 2.
// GAT collapsed via wa = W_gat @ a and Wbig = [fusion_W[0:129]; W_gat x fusion_W[129:]].
// GEMMs: bf16 MFMA hi/lo split (3 passes), 16 rows/block, full-N per block (X read once).
// GRU: single fused kernel (rz K=512 GEMM + n-gate 2x K=256) with gates+LN in epilogue.

typedef unsigned short u16;
typedef unsigned int   u32;
typedef __attribute__((ext_vector_type(8))) short bf16x8;
typedef __attribute__((ext_vector_type(4))) float f32x4;

#define KFUSE  672   // 641 padded to 21*32
#define ACT_TOT (8192*16)

__device__ __forceinline__ u16 f2bf(float x){
  u32 u = __float_as_uint(x);
  u += 0x7fffu + ((u >> 16) & 1u);   // round-to-nearest-even
  return (u16)(u >> 16);
}
__device__ __forceinline__ float bf2f(u16 h){ return __uint_as_float(((u32)h) << 16); }

// ---------- tiny preprocessing kernels ----------

__global__ void k_probe(const unsigned char* __restrict__ m, int* flag){
  if(threadIdx.x == 0){
    int s = 0;
    for(int i = 1; i < 256; i += 4) s += m[i];
    *flag = (s == 0) ? 1 : 0;   // 1 => 4-byte mask elements
  }
}

// wa_src[k][h], wa_dst[k][h]
__global__ void k_wa(const float* __restrict__ Wg, const float* __restrict__ ag,
                     float* __restrict__ was, float* __restrict__ wad){
  int t = threadIdx.x;            // 512
  int k = t & 127, h = t >> 7;
  float s = 0.f, d = 0.f;
  for(int f = 0; f < 64; ++f){
    float w = Wg[k*256 + h*64 + f];
    s += w * ag[h*128 + f];
    d += w * ag[h*128 + 64 + f];
  }
  was[k*4 + h] = s; wad[k*4 + h] = d;
}

// Wbig (672 x 256): rows 0..128 = fusion_W; 129+h*128+k = W_gat x fusion_W; pad rows 0.
__global__ void k_wbig(const float* __restrict__ fW, const float* __restrict__ Wg,
                       float* __restrict__ wbig){
  int r = blockIdx.x, j = threadIdx.x;  // 672 x 256
  float v;
  if(r < 129) v = fW[r*256 + j];
  else if(r < 641){
    int h = (r - 129) >> 7, kk = (r - 129) & 127;
    float s = 0.f;
    for(int f = 0; f < 64; ++f) s += Wg[kk*256 + h*64 + f] * fW[(129 + h*64 + f)*256 + j];
    v = s;
  } else v = 0.f;
  wbig[r*256 + j] = v;
}

// fp32 weight slice -> MFMA B-fragment order, hi/lo bf16.
// frag f=(kt,nt): lane l, elem i <-> src[(kt*32+(l>>4)*8+i)*ld + col0 + nt*16 + (l&15)]
__global__ void k_frag(const float* __restrict__ src, int ld, int col0, int NT,
                       u16* __restrict__ dhi, u16* __restrict__ dlo){
  int f = blockIdx.x, l = threadIdx.x;   // 64 threads
  int kt = f / NT, nt = f % NT;
  int kbase = kt*32 + (l >> 4)*8, n = col0 + nt*16 + (l & 15);
  size_t o = ((size_t)f*64 + l)*8;
  for(int i = 0; i < 8; ++i){
    float w = src[(size_t)(kbase + i)*ld + n];
    u16 h = f2bf(w);
    dhi[o + i] = h;
    dlo[o + i] = f2bf(w - bf2f(h));
  }
}

// fp32 -> (hi,lo) bf16, 8 elems/thread
__global__ void k_split(const float* __restrict__ x, u16* __restrict__ hi,
                        u16* __restrict__ lo, int n8){
  int i = blockIdx.x*blockDim.x + threadIdx.x;
  if(i >= n8) return;
  const float4* p = (const float4*)x + (size_t)i*2;
  float4 v0 = p[0], v1 = p[1];
  float vv[8] = {v0.x,v0.y,v0.z,v0.w,v1.x,v1.y,v1.z,v1.w};
  u16 h8[8], l8[8];
  #pragma unroll
  for(int q = 0; q < 8; ++q){ u16 h = f2bf(vv[q]); h8[q] = h; l8[q] = f2bf(vv[q] - bf2f(h)); }
  uint4 uh = { (u32)h8[0] | ((u32)h8[1]<<16), (u32)h8[2] | ((u32)h8[3]<<16),
               (u32)h8[4] | ((u32)h8[5]<<16), (u32)h8[6] | ((u32)h8[7]<<16) };
  uint4 ul = { (u32)l8[0] | ((u32)l8[1]<<16), (u32)l8[2] | ((u32)l8[3]<<16),
               (u32)l8[4] | ((u32)l8[5]<<16), (u32)l8[6] | ((u32)l8[7]<<16) };
  *(uint4*)(hi + (size_t)i*8) = uh;
  *(uint4*)(lo + (size_t)i*8) = ul;
}

// ---------- GAT kernel: one block per batch row, 40.0 KB LDS (4 blocks/CU) ----------
__global__ __launch_bounds__(256) void k_gat(
    const float* __restrict__ nbg, const float* __restrict__ node,
    const void* __restrict__ maskp, const int* __restrict__ flagp,
    const float* __restrict__ was, const float* __restrict__ wad,
    u16* __restrict__ xhi, u16* __restrict__ xlo)
{
  __shared__ float s_nb[8192];     // [n][x] float4-chunks, x = c ^ (n&31) swizzle
  __shared__ float s_wad[512];
  __shared__ float s_u[1040];      // union: stage1 partials [c][n][h] (1024) + esp (16) | stage3 partials (1024)
  __shared__ float s_alpha[256];   // [h][n]
  int b = blockIdx.x, t = threadIdx.x;
  const float* nb = nbg + (size_t)b*8192;
  const int isint = *flagp;

  s_wad[t] = wad[t]; s_wad[t+256] = wad[t+256];

  // enc part of x_cat: [sin, cos, node_obs[1:128]] + zero pad 641..671
  if(t < 129){
    float v;
    if(t < 2){
      float ph = node[(size_t)b*128] * (6.2831853071795864769f / 24.0f);
      v = (t == 0) ? sinf(ph) : cosf(ph);
    } else v = node[(size_t)b*128 + (t-1)];
    u16 h = f2bf(v);
    size_t o = (size_t)b*KFUSE + t;
    xhi[o] = h; xlo[o] = f2bf(v - bf2f(h));
  } else if(t < 160){
    size_t o = (size_t)b*KFUSE + 641 + (t - 129);
    xhi[o] = 0; xlo[o] = 0;
  }
  __syncthreads();

  // stage 1: load nb (swizzled to LDS) + e_dst partials over k-quarters
  int n = t & 63, c = t >> 6;
  float ad0=0.f, ad1=0.f, ad2=0.f, ad3=0.f;
  float as0=0.f, as1=0.f, as2=0.f, as3=0.f;
  bool row0 = (n == 0);
  #pragma unroll
  for(int q = 0; q < 8; ++q){
    float4 v = *(const float4*)(nb + n*128 + c*32 + q*4);
    int xcol = (c*8 + q) ^ (n & 31);
    *(float4*)(s_nb + (n*32 + xcol)*4) = v;
    float vv[4] = {v.x, v.y, v.z, v.w};
    #pragma unroll
    for(int i2 = 0; i2 < 4; ++i2){
      int k = c*32 + q*4 + i2;
      float4 wd = *(const float4*)(s_wad + k*4);
      float x = vv[i2];
      ad0 += x*wd.x; ad1 += x*wd.y; ad2 += x*wd.z; ad3 += x*wd.w;
      if(row0){
        float4 wsv = *(const float4*)(was + k*4);
        as0 += x*wsv.x; as1 += x*wsv.y; as2 += x*wsv.z; as3 += x*wsv.w;
      }
    }
  }
  s_u[(c*64+n)*4+0]=ad0; s_u[(c*64+n)*4+1]=ad1; s_u[(c*64+n)*4+2]=ad2; s_u[(c*64+n)*4+3]=ad3;
  if(row0){ s_u[1024+c*4+0]=as0; s_u[1024+c*4+1]=as1; s_u[1024+c*4+2]=as2; s_u[1024+c*4+3]=as3; }
  __syncthreads();

  // stage 2 + softmax: thread t -> (h = t>>6 == wave id, n = lane)
  {
    int n2 = t & 63, h2 = t >> 6;
    float ed = s_u[(0*64+n2)*4+h2] + s_u[(1*64+n2)*4+h2]
             + s_u[(2*64+n2)*4+h2] + s_u[(3*64+n2)*4+h2];
    float es = s_u[1024+h2] + s_u[1028+h2] + s_u[1032+h2] + s_u[1036+h2];
    float e = es + ed;
    e = (e > 0.f) ? e : 0.2f*e;
    bool valid;
    if(isint) valid = ((const u32*)maskp)[(size_t)b*64 + n2] != 0u;
    else      valid = ((const unsigned char*)maskp)[(size_t)b*64 + n2] != 0;
    float ev = valid ? e : -1e30f;
    float m = ev;
    for(int off = 32; off; off >>= 1) m = fmaxf(m, __shfl_xor(m, off));
    float p = (ev > -1e29f) ? expf(ev - m) : 0.f;
    float s = p;
    for(int off = 32; off; off >>= 1) s += __shfl_xor(s, off);
    s_alpha[t] = p / s;   // [h][n]
  }
  __syncthreads();

  // stage 3: agg[h][k] = sum_n alpha[h][n]*nb[n][k], float4-vectorized, 2 n-halves
  {
    int c = t & 31, hh = (t >> 5) & 3, half = t >> 7;
    float4 p = {0.f,0.f,0.f,0.f};
    int n0 = half*32;
    #pragma unroll 8
    for(int nn = n0; nn < n0+32; ++nn){
      float a = s_alpha[hh*64 + nn];
      float4 v = *(const float4*)(s_nb + (nn*32 + (c ^ (nn & 31)))*4);
      p.x += a*v.x; p.y += a*v.y; p.z += a*v.z; p.w += a*v.w;
    }
    *(float4*)(s_u + ((hh*2+half)*32 + c)*4) = p;
  }
  __syncthreads();
  if(t < 128){
    int c = t & 31, hh = t >> 5;
    float4 pa = *(const float4*)(s_u + ((hh*2+0)*32 + c)*4);
    float4 pb = *(const float4*)(s_u + ((hh*2+1)*32 + c)*4);
    float vv[4] = {pa.x+pb.x, pa.y+pb.y, pa.z+pb.z, pa.w+pb.w};
    size_t o = (size_t)b*KFUSE + 129 + hh*128 + c*4;
    #pragma unroll
    for(int i = 0; i < 4; ++i){
      u16 h = f2bf(vv[i]);
      xhi[o+i] = h; xlo[o+i] = f2bf(vv[i] - bf2f(h));
    }
  }
}

// ---------- split-bf16 MFMA GEMM: 16 rows/block, full N, X read once ----------
// wave w owns cols [(w*NPW)*16, (w*NPW+NPW)*16); NTOT = NPW*64
// EPI 0: relu -> hi/lo bf16; EPI 2: f32 (no relu... see flag) ; relu applied for both here
template<int KT, int NPW, int EPI>
__global__ __launch_bounds__(256) void k_gemm2(
    const u16* __restrict__ xhi, const u16* __restrict__ xlo,
    const u16* __restrict__ wfhi, const u16* __restrict__ wflo,
    const float* __restrict__ bias,
    float* __restrict__ outf, u16* __restrict__ ohi, u16* __restrict__ olo)
{
  const int KP = KT*32, NTOT = NPW*64, NT = NPW*4;
  int l = threadIdx.x & 63, w = threadIdx.x >> 6;
  int m0 = blockIdx.x*16;
  f32x4 acc[NPW];
  #pragma unroll
  for(int j = 0; j < NPW; ++j) acc[j] = (f32x4){0.f,0.f,0.f,0.f};
  const size_t arow = (size_t)(m0 + (l & 15))*KP + (size_t)((l >> 4)*8);
  for(int kt = 0; kt < KT; ++kt){
    bf16x8 ah = *(const bf16x8*)(xhi + arow + kt*32);
    bf16x8 al = *(const bf16x8*)(xlo + arow + kt*32);
    #pragma unroll
    for(int j = 0; j < NPW; ++j){
      size_t bo = ((size_t)(kt*NT + w*NPW + j)*64 + l)*8;
      bf16x8 bh = *(const bf16x8*)(wfhi + bo);
      bf16x8 bl = *(const bf16x8*)(wflo + bo);
      acc[j] = __builtin_amdgcn_mfma_f32_16x16x32_bf16(ah, bh, acc[j], 0, 0, 0);
      acc[j] = __builtin_amdgcn_mfma_f32_16x16x32_bf16(ah, bl, acc[j], 0, 0, 0);
      acc[j] = __builtin_amdgcn_mfma_f32_16x16x32_bf16(al, bh, acc[j], 0, 0, 0);
    }
  }
  int r0 = m0 + (l >> 4)*4;
  #pragma unroll
  for(int j = 0; j < NPW; ++j){
    int col = (w*NPW + j)*16 + (l & 15);
    float bv = bias[col];
    #pragma unroll
    for(int q = 0; q < 4; ++q){
      float y = acc[j][q] + bv;
      int row = r0 + q;
      y = fmaxf(y, 0.f);
      if(EPI == 0){
        u16 h = f2bf(y);
        size_t o = (size_t)row*NTOT + col;
        ohi[o] = h; olo[o] = f2bf(y - bf2f(h));
      } else {
        outf[(size_t)row*NTOT + col] = y;
      }
    }
  }
}

// ---------- fused GRU: rz K=512 GEMM + n-gate 2x K=256 GEMM + gates + LN ----------
// wave w owns gate-cols [w*64, w*64+64). All gate components in registers.
__global__ __launch_bounds__(256) void k_gru(
    const u16* __restrict__ fsh, const u16* __restrict__ fsl,
    const u16* __restrict__ hhi, const u16* __restrict__ hlo,
    const u16* __restrict__ wrzh, const u16* __restrict__ wrzl,
    const u16* __restrict__ winh, const u16* __restrict__ winl,
    const u16* __restrict__ whnh, const u16* __restrict__ whnl,
    const float* __restrict__ bih, const float* __restrict__ bhh,
    const float* __restrict__ hidden, const float* __restrict__ lng,
    const float* __restrict__ lnb,
    float* __restrict__ hout, u16* __restrict__ belh, u16* __restrict__ bell)
{
  __shared__ float s_s1[64], s_s2[64], s_mu[16], s_rs[16];
  int l = threadIdx.x & 63, w = threadIdx.x >> 6;
  int m0 = blockIdx.x*16;
  f32x4 ar[4], az[4], aa[4], ab[4];
  #pragma unroll
  for(int j = 0; j < 4; ++j){
    ar[j] = (f32x4){0.f,0.f,0.f,0.f}; az[j] = (f32x4){0.f,0.f,0.f,0.f};
    aa[j] = (f32x4){0.f,0.f,0.f,0.f}; ab[j] = (f32x4){0.f,0.f,0.f,0.f};
  }
  const size_t arow = (size_t)(m0 + (l & 15))*256 + (size_t)((l >> 4)*8);
  // rz gates: K=512 over [fused | h], W-frags NT=32 (cols 0..511 of gate space)
  for(int kt = 0; kt < 16; ++kt){
    const u16* xh = (kt < 8) ? fsh : hhi;
    const u16* xl = (kt < 8) ? fsl : hlo;
    int koff = (kt & 7)*32;
    bf16x8 ah = *(const bf16x8*)(xh + arow + koff);
    bf16x8 al = *(const bf16x8*)(xl + arow + koff);
    #pragma unroll
    for(int j = 0; j < 4; ++j){
      size_t bo = ((size_t)(kt*32 + w*4 + j)*64 + l)*8;
      bf16x8 bh = *(const bf16x8*)(wrzh + bo);
      bf16x8 bl = *(const bf16x8*)(wrzl + bo);
      ar[j] = __builtin_amdgcn_mfma_f32_16x16x32_bf16(ah, bh, ar[j], 0, 0, 0);
      ar[j] = __builtin_amdgcn_mfma_f32_16x16x32_bf16(ah, bl, ar[j], 0, 0, 0);
      ar[j] = __builtin_amdgcn_mfma_f32_16x16x32_bf16(al, bh, ar[j], 0, 0, 0);
      size_t bo2 = ((size_t)(kt*32 + 16 + w*4 + j)*64 + l)*8;
      bf16x8 bh2 = *(const bf16x8*)(wrzh + bo2);
      bf16x8 bl2 = *(const bf16x8*)(wrzl + bo2);
      az[j] = __builtin_amdgcn_mfma_f32_16x16x32_bf16(ah, bh2, az[j], 0, 0, 0);
      az[j] = __builtin_amdgcn_mfma_f32_16x16x32_bf16(ah, bl2, az[j], 0, 0, 0);
      az[j] = __builtin_amdgcn_mfma_f32_16x16x32_bf16(al, bh2, az[j], 0, 0, 0);
    }
  }
  // n gate: in = fused @ Wih_n, hn = h @ Whh_n (K=256 each, NT=16)
  for(int kt = 0; kt < 8; ++kt){
    int koff = kt*32;
    bf16x8 ah = *(const bf16x8*)(fsh + arow + koff);
    bf16x8 al = *(const bf16x8*)(fsl + arow + koff);
    bf16x8 gh = *(const bf16x8*)(hhi + arow + koff);
    bf16x8 gl = *(const bf16x8*)(hlo + arow + koff);
    #pragma unroll
    for(int j = 0; j < 4; ++j){
      size_t bo = ((size_t)(kt*16 + w*4 + j)*64 + l)*8;
      bf16x8 bh = *(const bf16x8*)(winh + bo);
      bf16x8 bl = *(const bf16x8*)(winl + bo);
      aa[j] = __builtin_amdgcn_mfma_f32_16x16x32_bf16(ah, bh, aa[j], 0, 0, 0);
      aa[j] = __builtin_amdgcn_mfma_f32_16x16x32_bf16(ah, bl, aa[j], 0, 0, 0);
      aa[j] = __builtin_amdgcn_mfma_f32_16x16x32_bf16(al, bh, aa[j], 0, 0, 0);
      bf16x8 ch = *(const bf16x8*)(whnh + bo);
      bf16x8 cl2 = *(const bf16x8*)(whnl + bo);
      ab[j] = __builtin_amdgcn_mfma_f32_16x16x32_bf16(gh, ch, ab[j], 0, 0, 0);
      ab[j] = __builtin_amdgcn_mfma_f32_16x16x32_bf16(gh, cl2, ab[j], 0, 0, 0);
      ab[j] = __builtin_amdgcn_mfma_f32_16x16x32_bf16(gl, ch, ab[j], 0, 0, 0);
    }
  }
  // epilogue: gates + h_new, per-row LN stats
  int cl = l & 15, rq = l >> 4;
  float hnew[4][4];
  float s1[4] = {0.f,0.f,0.f,0.f}, s2[4] = {0.f,0.f,0.f,0.f};
  #pragma unroll
  for(int j = 0; j < 4; ++j){
    int col = w*64 + j*16 + cl;
    float br = bih[col] + bhh[col];
    float bz = bih[256+col] + bhh[256+col];
    float bi = bih[512+col];
    float bh2 = bhh[512+col];
    #pragma unroll
    for(int q = 0; q < 4; ++q){
      int row = m0 + rq*4 + q;
      float rs = ar[j][q] + br;
      float zs = az[j][q] + bz;
      float in_ = aa[j][q] + bi;
      float hn  = ab[j][q] + bh2;
      float h   = hidden[(size_t)row*256 + col];
      float r = 1.f/(1.f + expf(-rs));
      float z = 1.f/(1.f + expf(-zs));
      float nv = tanhf(in_ + r*hn);
      float hv = (1.f - z)*nv + z*h;
      hnew[j][q] = hv;
      hout[(size_t)row*256 + col] = hv;
      s1[q] += hv; s2[q] += hv*hv;
    }
  }
  #pragma unroll
  for(int q = 0; q < 4; ++q){
    for(int off = 1; off < 16; off <<= 1){
      s1[q] += __shfl_xor(s1[q], off);
      s2[q] += __shfl_xor(s2[q], off);
    }
  }
  if(cl == 0){
    #pragma unroll
    for(int q = 0; q < 4; ++q){
      s_s1[w*16 + rq*4 + q] = s1[q];
      s_s2[w*16 + rq*4 + q] = s2[q];
    }
  }
  __syncthreads();
  if(threadIdx.x < 16){
    int rr = threadIdx.x;
    float t1 = s_s1[rr] + s_s1[16+rr] + s_s1[32+rr] + s_s1[48+rr];
    float t2 = s_s2[rr] + s_s2[16+rr] + s_s2[32+rr] + s_s2[48+rr];
    float mu = t1 * (1.f/256.f);
    float var = t2 * (1.f/256.f) - mu*mu;
    s_mu[rr] = mu;
    s_rs[rr] = rsqrtf(var + 1e-5f);
  }
  __syncthreads();
  #pragma unroll
  for(int j = 0; j < 4; ++j){
    int col = w*64 + j*16 + cl;
    float g = lng[col], bb = lnb[col];
    #pragma unroll
    for(int q = 0; q < 4; ++q){
      int rloc = rq*4 + q;
      float bel = (hnew[j][q] - s_mu[rloc]) * s_rs[rloc] * g + bb;
      u16 hb = f2bf(bel);
      size_t o = (size_t)(m0 + rloc)*256 + col;
      belh[o] = hb; bell[o] = f2bf(bel - bf2f(hb));
    }
  }
}

// ---------- W3 head + project_power (16 rows/block, 16 lanes/row) ----------
__global__ __launch_bounds__(256) void k_head(
    const float* __restrict__ x2, const float* __restrict__ W3,
    const float* __restrict__ b3, float* __restrict__ act)
{
  __shared__ float sW[2048];
  int t = threadIdx.x;
  for(int i = t; i < 2048; i += 256) sW[i] = W3[i];
  __syncthreads();
  int rl = t >> 4, j = t & 15;
  int b = blockIdx.x*16 + rl;
  const float* xr = x2 + (size_t)b*128;
  float raw = b3[j];
  #pragma unroll 8
  for(int k4 = 0; k4 < 32; ++k4){
    float4 v = *(const float4*)(xr + k4*4);
    raw += v.x*sW[(k4*4+0)*16 + j] + v.y*sW[(k4*4+1)*16 + j]
         + v.z*sW[(k4*4+2)*16 + j] + v.w*sW[(k4*4+3)*16 + j];
  }
  float c0 = fminf(fmaxf(raw, 0.f), 0.5f);
  float tot = c0;
  for(int off = 8; off; off >>= 1) tot += __shfl_xor(tot, off);
  float mx = raw;
  for(int off = 8; off; off >>= 1) mx = fmaxf(mx, __shfl_xor(mx, off));
  bool feas = (tot <= 1.0f);
  float lo = 0.f, hi = fmaxf(mx, 0.f);
  for(int it = 0; it < 60; ++it){
    float mid = 0.5f*(lo + hi);
    float s = fminf(fmaxf(raw - mid, 0.f), 0.5f);
    for(int off = 8; off; off >>= 1) s += __shfl_xor(s, off);
    bool over = s > 1.0f;
    lo = over ? mid : lo;
    hi = over ? hi : mid;
  }
  float muv = feas ? 0.f : hi;
  act[(size_t)b*16 + j] = fminf(fmaxf(raw - muv, 0.f), 0.5f);
}

// ---------- workspace layout (bytes) ----------
#define OFF_FLAG   0u
#define OFF_WAS    256u
#define OFF_WAD    2304u
#define OFF_WBIG   4352u
#define OFF_FFH    692480u
#define OFF_FFL    1036544u
#define OFF_WRZH   1380608u
#define OFF_WRZL   1904896u
#define OFF_WINH   2429184u
#define OFF_WINL   2560256u
#define OFF_WHNH   2691328u
#define OFF_WHNL   2822400u
#define OFF_F1H    2953472u
#define OFF_F1L    3084544u
#define OFF_F2H    3215616u
#define OFF_F2L    3281152u
#define OFF_XCATH  3346688u
#define OFF_XCATL  14356736u
#define OFF_FSH    25366784u
#define OFF_FSL    29561088u
#define OFF_HHI    33755392u
#define OFF_HLO    37949696u
#define OFF_X1H    42144000u
#define OFF_X1L    46338304u
#define OFF_X2     50532608u
#define OFF_BELH   54726912u
#define OFF_BELL   58921216u
// total: 63,115,520 bytes

extern "C" void kernel_launch(void* const* d_in, const int* in_sizes, int n_in,
                              void* d_out, int out_size, void* d_ws, size_t ws_size,
                              hipStream_t stream){
  const float* node   = (const float*)d_in[0];
  const float* nbr    = (const float*)d_in[1];
  const void*  mask   = d_in[2];
  const float* hidden = (const float*)d_in[3];
  const float* Wg     = (const float*)d_in[4];
  const float* ag     = (const float*)d_in[5];
  const float* fW     = (const float*)d_in[6];
  const float* fb     = (const float*)d_in[7];
  const float* Wih    = (const float*)d_in[8];
  const float* bih    = (const float*)d_in[9];
  const float* Whh    = (const float*)d_in[10];
  const float* bhh    = (const float*)d_in[11];
  const float* lng    = (const float*)d_in[12];
  const float* lnb    = (const float*)d_in[13];
  const float* W1     = (const float*)d_in[14];
  const float* b1     = (const float*)d_in[15];
  const float* W2     = (const float*)d_in[16];
  const float* b2     = (const float*)d_in[17];
  const float* W3     = (const float*)d_in[18];
  const float* b3     = (const float*)d_in[19];
  char* ws = (char*)d_ws;
  float* out = (float*)d_out;

  int*   flag = (int*)  (ws + OFF_FLAG);
  float* was  = (float*)(ws + OFF_WAS);
  float* wad  = (float*)(ws + OFF_WAD);
  float* wbig = (float*)(ws + OFF_WBIG);
  u16* ffh  = (u16*)(ws + OFF_FFH);   u16* ffl  = (u16*)(ws + OFF_FFL);
  u16* wrzh = (u16*)(ws + OFF_WRZH);  u16* wrzl = (u16*)(ws + OFF_WRZL);
  u16* winh = (u16*)(ws + OFF_WINH);  u16* winl = (u16*)(ws + OFF_WINL);
  u16* whnh = (u16*)(ws + OFF_WHNH);  u16* whnl = (u16*)(ws + OFF_WHNL);
  u16* f1h  = (u16*)(ws + OFF_F1H);   u16* f1l  = (u16*)(ws + OFF_F1L);
  u16* f2h  = (u16*)(ws + OFF_F2H);   u16* f2l  = (u16*)(ws + OFF_F2L);
  u16* xh   = (u16*)(ws + OFF_XCATH); u16* xl   = (u16*)(ws + OFF_XCATL);
  u16* fsh  = (u16*)(ws + OFF_FSH);   u16* fsl  = (u16*)(ws + OFF_FSL);
  u16* hhi  = (u16*)(ws + OFF_HHI);   u16* hlo  = (u16*)(ws + OFF_HLO);
  u16* x1h  = (u16*)(ws + OFF_X1H);   u16* x1l  = (u16*)(ws + OFF_X1L);
  float* x2 = (float*)(ws + OFF_X2);
  u16* beh  = (u16*)(ws + OFF_BELH);  u16* bel  = (u16*)(ws + OFF_BELL);

  // preprocessing (constant folding of weights)
  k_probe<<<1, 64, 0, stream>>>((const unsigned char*)mask, flag);
  k_wa<<<1, 512, 0, stream>>>(Wg, ag, was, wad);
  k_wbig<<<672, 256, 0, stream>>>(fW, Wg, wbig);
  k_frag<<<21*16, 64, 0, stream>>>(wbig, 256, 0, 16, ffh, ffl);
  // rz weights: [Wih_rz (kt 0..7); Whh_rz (kt 8..15)], NT=32
  k_frag<<<8*32, 64, 0, stream>>>(Wih, 768, 0, 32, wrzh, wrzl);
  k_frag<<<8*32, 64, 0, stream>>>(Whh, 768, 0, 32, wrzh + 131072, wrzl + 131072);
  k_frag<<<8*16, 64, 0, stream>>>(Wih, 768, 512, 16, winh, winl);
  k_frag<<<8*16, 64, 0, stream>>>(Whh, 768, 512, 16, whnh, whnl);
  k_frag<<<8*16, 64, 0, stream>>>(W1, 256, 0, 16, f1h, f1l);
  k_frag<<<8*8,  64, 0, stream>>>(W2, 128, 0, 8, f2h, f2l);
  k_split<<<1024, 256, 0, stream>>>(hidden, hhi, hlo, 262144);

  // GAT -> x_cat (hi/lo)
  k_gat<<<8192, 256, 0, stream>>>(nbr, node, mask, flag, was, wad, xh, xl);

  // fused = relu(x_cat @ Wbig + fb)
  k_gemm2<21,4,0><<<512, 256, 0, stream>>>(xh, xl, ffh, ffl, fb, nullptr, fsh, fsl);
  // GRU + LN fused
  k_gru<<<512, 256, 0, stream>>>(fsh, fsl, hhi, hlo, wrzh, wrzl, winh, winl,
                                 whnh, whnl, bih, bhh, hidden, lng, lnb,
                                 out + ACT_TOT, beh, bel);
  // MLP
  k_gemm2<8,4,0><<<512, 256, 0, stream>>>(beh, bel, f1h, f1l, b1, nullptr, x1h, x1l);
  k_gemm2<8,2,2><<<512, 256, 0, stream>>>(x1h, x1l, f2h, f2l, b2, x2, nullptr, nullptr);
  // head + projection
  k_head<<<512, 256, 0, stream>>>(x2, W3, b3, out);
}

// Round 3
// 263.439 us; speedup vs baseline: 1.3975x; 1.3975x over previous
//
#include <hip/hip_runtime.h>
#include <hip/hip_bf16.h>

// ActorNetwork fused pipeline for MI355X — round 3.
// GAT collapsed via wa = W_gat @ a and Wbig = [fusion_W[0:129]; W_gat x fusion_W[129:]].
// k_gat v3: coalesced global->LDS copy, all compute from LDS (fixes 512B-strided loads).
// GEMMs: bf16 MFMA hi/lo split (3 passes), ROWF=2 + col-split (B read once per 32 rows).

typedef unsigned short u16;
typedef unsigned int   u32;
typedef __attribute__((ext_vector_type(8))) short bf16x8;
typedef __attribute__((ext_vector_type(4))) float f32x4;

#define KFUSE  672   // 641 padded to 21*32
#define ACT_TOT (8192*16)

__device__ __forceinline__ u16 f2bf(float x){
  u32 u = __float_as_uint(x);
  u += 0x7fffu + ((u >> 16) & 1u);   // round-to-nearest-even
  return (u16)(u >> 16);
}
__device__ __forceinline__ float bf2f(u16 h){ return __uint_as_float(((u32)h) << 16); }

// ---------- tiny preprocessing kernels ----------

__global__ void k_probe(const unsigned char* __restrict__ m, int* flag){
  if(threadIdx.x == 0){
    int s = 0;
    for(int i = 1; i < 256; i += 4) s += m[i];
    *flag = (s == 0) ? 1 : 0;   // 1 => 4-byte mask elements
  }
}

// wa_src[k][h], wa_dst[k][h]
__global__ void k_wa(const float* __restrict__ Wg, const float* __restrict__ ag,
                     float* __restrict__ was, float* __restrict__ wad){
  int t = threadIdx.x;            // 512
  int k = t & 127, h = t >> 7;
  float s = 0.f, d = 0.f;
  for(int f = 0; f < 64; ++f){
    float w = Wg[k*256 + h*64 + f];
    s += w * ag[h*128 + f];
    d += w * ag[h*128 + 64 + f];
  }
  was[k*4 + h] = s; wad[k*4 + h] = d;
}

// Wbig (672 x 256): rows 0..128 = fusion_W; 129+h*128+k = W_gat x fusion_W; pad rows 0.
__global__ void k_wbig(const float* __restrict__ fW, const float* __restrict__ Wg,
                       float* __restrict__ wbig){
  int r = blockIdx.x, j = threadIdx.x;  // 672 x 256
  float v;
  if(r < 129) v = fW[r*256 + j];
  else if(r < 641){
    int h = (r - 129) >> 7, kk = (r - 129) & 127;
    float s = 0.f;
    for(int f = 0; f < 64; ++f) s += Wg[kk*256 + h*64 + f] * fW[(129 + h*64 + f)*256 + j];
    v = s;
  } else v = 0.f;
  wbig[r*256 + j] = v;
}

// fp32 weight slice -> MFMA B-fragment order, hi/lo bf16.
// frag f=(kt,nt): lane l, elem i <-> src[(kt*32+(l>>4)*8+i)*ld + col0 + nt*16 + (l&15)]
__global__ void k_frag(const float* __restrict__ src, int ld, int col0, int NT,
                       u16* __restrict__ dhi, u16* __restrict__ dlo){
  int f = blockIdx.x, l = threadIdx.x;   // 64 threads
  int kt = f / NT, nt = f % NT;
  int kbase = kt*32 + (l >> 4)*8, n = col0 + nt*16 + (l & 15);
  size_t o = ((size_t)f*64 + l)*8;
  for(int i = 0; i < 8; ++i){
    float w = src[(size_t)(kbase + i)*ld + n];
    u16 h = f2bf(w);
    dhi[o + i] = h;
    dlo[o + i] = f2bf(w - bf2f(h));
  }
}

// fp32 -> (hi,lo) bf16, 8 elems/thread
__global__ void k_split(const float* __restrict__ x, u16* __restrict__ hi,
                        u16* __restrict__ lo, int n8){
  int i = blockIdx.x*blockDim.x + threadIdx.x;
  if(i >= n8) return;
  const float4* p = (const float4*)x + (size_t)i*2;
  float4 v0 = p[0], v1 = p[1];
  float vv[8] = {v0.x,v0.y,v0.z,v0.w,v1.x,v1.y,v1.z,v1.w};
  u16 h8[8], l8[8];
  #pragma unroll
  for(int q = 0; q < 8; ++q){ u16 h = f2bf(vv[q]); h8[q] = h; l8[q] = f2bf(vv[q] - bf2f(h)); }
  uint4 uh = { (u32)h8[0] | ((u32)h8[1]<<16), (u32)h8[2] | ((u32)h8[3]<<16),
               (u32)h8[4] | ((u32)h8[5]<<16), (u32)h8[6] | ((u32)h8[7]<<16) };
  uint4 ul = { (u32)l8[0] | ((u32)l8[1]<<16), (u32)l8[2] | ((u32)l8[3]<<16),
               (u32)l8[4] | ((u32)l8[5]<<16), (u32)l8[6] | ((u32)l8[7]<<16) };
  *(uint4*)(hi + (size_t)i*8) = uh;
  *(uint4*)(lo + (size_t)i*8) = ul;
}

// ---------- GAT kernel v3: one block per batch row, coalesced load, 39.9 KB LDS ----------
__global__ __launch_bounds__(256) void k_gat(
    const float* __restrict__ nbg, const float* __restrict__ node,
    const void* __restrict__ maskp, const int* __restrict__ flagp,
    const float* __restrict__ was, const float* __restrict__ wad,
    u16* __restrict__ xhi, u16* __restrict__ xlo)
{
  __shared__ float s_nb[8192];     // [n][ch^(n&31)] float4 chunks
  __shared__ float s_wad[512];
  __shared__ float s_ep[1024];     // ed partials [c][n][h]
  __shared__ float s_alpha[256];   // [h][n]
  int b = blockIdx.x, t = threadIdx.x;
  const float* nb = nbg + (size_t)b*8192;
  const int isint = *flagp;

  s_wad[t] = wad[t]; s_wad[t+256] = wad[t+256];

  // coalesced copy nb -> s_nb (swizzled float4 chunks); thread t copies f = q*256+t
  #pragma unroll
  for(int q = 0; q < 8; ++q){
    int f = q*256 + t;             // float4 index 0..2047
    int n = f >> 5, ch = f & 31;
    float4 v = *(const float4*)(nb + f*4);
    *(float4*)(s_nb + (n*32 + (ch ^ (n & 31)))*4) = v;
  }

  // enc part of x_cat: [sin, cos, node_obs[1:128]] + zero pad 641..671 (global-only)
  if(t < 129){
    float v;
    if(t < 2){
      float ph = node[(size_t)b*128] * (6.2831853071795864769f / 24.0f);
      v = (t == 0) ? sinf(ph) : cosf(ph);
    } else v = node[(size_t)b*128 + (t-1)];
    u16 h = f2bf(v);
    size_t o = (size_t)b*KFUSE + t;
    xhi[o] = h; xlo[o] = f2bf(v - bf2f(h));
  } else if(t < 160){
    size_t o = (size_t)b*KFUSE + 641 + (t - 129);
    xhi[o] = 0; xlo[o] = 0;
  }
  __syncthreads();

  // phase 1b: ed partials from LDS. thread (n = t&63, c = t>>6) handles k-quarter c.
  {
    int n = t & 63, c = t >> 6;
    float adx = 0.f, ady = 0.f, adz = 0.f, adw = 0.f;
    #pragma unroll
    for(int q = 0; q < 8; ++q){
      int ch = c*8 + q;
      float4 v = *(const float4*)(s_nb + (n*32 + (ch ^ (n & 31)))*4);
      float vv[4] = {v.x, v.y, v.z, v.w};
      #pragma unroll
      for(int i2 = 0; i2 < 4; ++i2){
        int k = ch*4 + i2;
        float4 wd = *(const float4*)(s_wad + k*4);   // wave-uniform: broadcast
        adx += vv[i2]*wd.x; ady += vv[i2]*wd.y; adz += vv[i2]*wd.z; adw += vv[i2]*wd.w;
      }
    }
    float4 ad = {adx, ady, adz, adw};
    *(float4*)(s_ep + (c*64 + n)*4) = ad;
  }
  __syncthreads();

  // phase 2: e_src (lane-parallel reduce) + softmax. wave = head h2, lane = neighbor n2.
  {
    int n2 = t & 63, h2 = t >> 6;
    float es = 0.f;
    #pragma unroll
    for(int ii = 0; ii < 2; ++ii){
      int k = n2*2 + ii;
      float v0 = s_nb[(k >> 2)*4 + (k & 3)];   // row 0: swizzle is identity
      es += v0 * was[k*4 + h2];
    }
    for(int off = 32; off; off >>= 1) es += __shfl_xor(es, off);
    float ed = s_ep[n2*4 + h2] + s_ep[(64+n2)*4 + h2]
             + s_ep[(128+n2)*4 + h2] + s_ep[(192+n2)*4 + h2];
    float e = es + ed;
    e = (e > 0.f) ? e : 0.2f*e;
    bool valid;
    if(isint) valid = ((const u32*)maskp)[(size_t)b*64 + n2] != 0u;
    else      valid = ((const unsigned char*)maskp)[(size_t)b*64 + n2] != 0;
    float ev = valid ? e : -1e30f;
    float m = ev;
    for(int off = 32; off; off >>= 1) m = fmaxf(m, __shfl_xor(m, off));
    float p = valid ? expf(ev - m) : 0.f;
    float s = p;
    for(int off = 32; off; off >>= 1) s += __shfl_xor(s, off);
    s_alpha[t] = p / s;   // [h][n]
  }
  __syncthreads();

  // stage 3: thread (k = t&127, head-pair hp) accumulates over all 64 neighbors.
  {
    int k = t & 127, hp = (t >> 7)*2;
    int ch = k >> 2, sub = k & 3;
    float a0 = 0.f, a1 = 0.f;
    #pragma unroll 4
    for(int nn = 0; nn < 64; ++nn){
      float v = s_nb[(nn*32 + (ch ^ (nn & 31)))*4 + sub];
      a0 += v * s_alpha[hp*64 + nn];        // broadcast
      a1 += v * s_alpha[(hp+1)*64 + nn];
    }
    size_t o0 = (size_t)b*KFUSE + 129 + hp*128 + k;
    u16 h0 = f2bf(a0); xhi[o0] = h0; xlo[o0] = f2bf(a0 - bf2f(h0));
    size_t o1 = o0 + 128;
    u16 h1 = f2bf(a1); xhi[o1] = h1; xlo[o1] = f2bf(a1 - bf2f(h1));
  }
}

// ---------- split-bf16 MFMA GEMM: ROWF row-frags, col-split grid ----------
// block: rows [bx*16*ROWF, ...), cols [by*4*NPW*16, ...); wave w owns NPW col-frags.
// EPI 0: relu -> hi/lo bf16; EPI 2: relu -> f32
template<int KT, int NT_TOT, int NPW, int ROWF, int EPI>
__global__ __launch_bounds__(256) void k_gemm3(
    const u16* __restrict__ xhi, const u16* __restrict__ xlo,
    const u16* __restrict__ wfhi, const u16* __restrict__ wflo,
    const float* __restrict__ bias,
    float* __restrict__ outf, u16* __restrict__ ohi, u16* __restrict__ olo)
{
  const int KP = KT*32, NTOT = NT_TOT*16;
  int l = threadIdx.x & 63, w = threadIdx.x >> 6;
  int m0 = blockIdx.x * (16*ROWF);
  int ntbase = blockIdx.y * (4*NPW) + w*NPW;
  f32x4 acc[NPW][ROWF];
  #pragma unroll
  for(int j = 0; j < NPW; ++j)
    #pragma unroll
    for(int rf = 0; rf < ROWF; ++rf) acc[j][rf] = (f32x4){0.f,0.f,0.f,0.f};
  size_t arow[ROWF];
  #pragma unroll
  for(int rf = 0; rf < ROWF; ++rf)
    arow[rf] = (size_t)(m0 + rf*16 + (l & 15))*KP + (size_t)((l >> 4)*8);
  for(int kt = 0; kt < KT; ++kt){
    bf16x8 ah[ROWF], al[ROWF];
    #pragma unroll
    for(int rf = 0; rf < ROWF; ++rf){
      ah[rf] = *(const bf16x8*)(xhi + arow[rf] + kt*32);
      al[rf] = *(const bf16x8*)(xlo + arow[rf] + kt*32);
    }
    #pragma unroll
    for(int j = 0; j < NPW; ++j){
      size_t bo = ((size_t)(kt*NT_TOT + ntbase + j)*64 + l)*8;
      bf16x8 bh = *(const bf16x8*)(wfhi + bo);
      bf16x8 bl = *(const bf16x8*)(wflo + bo);
      #pragma unroll
      for(int rf = 0; rf < ROWF; ++rf){
        acc[j][rf] = __builtin_amdgcn_mfma_f32_16x16x32_bf16(ah[rf], bh, acc[j][rf], 0, 0, 0);
        acc[j][rf] = __builtin_amdgcn_mfma_f32_16x16x32_bf16(ah[rf], bl, acc[j][rf], 0, 0, 0);
        acc[j][rf] = __builtin_amdgcn_mfma_f32_16x16x32_bf16(al[rf], bh, acc[j][rf], 0, 0, 0);
      }
    }
  }
  #pragma unroll
  for(int j = 0; j < NPW; ++j){
    int col = (ntbase + j)*16 + (l & 15);
    float bv = bias[col];
    #pragma unroll
    for(int rf = 0; rf < ROWF; ++rf){
      int r0 = m0 + rf*16 + (l >> 4)*4;
      #pragma unroll
      for(int q = 0; q < 4; ++q){
        float y = fmaxf(acc[j][rf][q] + bv, 0.f);
        int row = r0 + q;
        if(EPI == 0){
          u16 h = f2bf(y);
          size_t o = (size_t)row*NTOT + col;
          ohi[o] = h; olo[o] = f2bf(y - bf2f(h));
        } else {
          outf[(size_t)row*NTOT + col] = y;
        }
      }
    }
  }
}

// ---------- fused GRU: rz K=512 GEMM + n-gate 2x K=256 GEMM + gates + LN ----------
__global__ __launch_bounds__(256) void k_gru(
    const u16* __restrict__ fsh, const u16* __restrict__ fsl,
    const u16* __restrict__ hhi, const u16* __restrict__ hlo,
    const u16* __restrict__ wrzh, const u16* __restrict__ wrzl,
    const u16* __restrict__ winh, const u16* __restrict__ winl,
    const u16* __restrict__ whnh, const u16* __restrict__ whnl,
    const float* __restrict__ bih, const float* __restrict__ bhh,
    const float* __restrict__ hidden, const float* __restrict__ lng,
    const float* __restrict__ lnb,
    float* __restrict__ hout, u16* __restrict__ belh, u16* __restrict__ bell)
{
  __shared__ float s_s1[64], s_s2[64], s_mu[16], s_rs[16];
  int l = threadIdx.x & 63, w = threadIdx.x >> 6;
  int m0 = blockIdx.x*16;
  f32x4 ar[4], az[4], aa[4], ab[4];
  #pragma unroll
  for(int j = 0; j < 4; ++j){
    ar[j] = (f32x4){0.f,0.f,0.f,0.f}; az[j] = (f32x4){0.f,0.f,0.f,0.f};
    aa[j] = (f32x4){0.f,0.f,0.f,0.f}; ab[j] = (f32x4){0.f,0.f,0.f,0.f};
  }
  const size_t arow = (size_t)(m0 + (l & 15))*256 + (size_t)((l >> 4)*8);
  for(int kt = 0; kt < 16; ++kt){
    const u16* xh = (kt < 8) ? fsh : hhi;
    const u16* xl = (kt < 8) ? fsl : hlo;
    int koff = (kt & 7)*32;
    bf16x8 ah = *(const bf16x8*)(xh + arow + koff);
    bf16x8 al = *(const bf16x8*)(xl + arow + koff);
    #pragma unroll
    for(int j = 0; j < 4; ++j){
      size_t bo = ((size_t)(kt*32 + w*4 + j)*64 + l)*8;
      bf16x8 bh = *(const bf16x8*)(wrzh + bo);
      bf16x8 bl = *(const bf16x8*)(wrzl + bo);
      ar[j] = __builtin_amdgcn_mfma_f32_16x16x32_bf16(ah, bh, ar[j], 0, 0, 0);
      ar[j] = __builtin_amdgcn_mfma_f32_16x16x32_bf16(ah, bl, ar[j], 0, 0, 0);
      ar[j] = __builtin_amdgcn_mfma_f32_16x16x32_bf16(al, bh, ar[j], 0, 0, 0);
      size_t bo2 = ((size_t)(kt*32 + 16 + w*4 + j)*64 + l)*8;
      bf16x8 bh2 = *(const bf16x8*)(wrzh + bo2);
      bf16x8 bl2 = *(const bf16x8*)(wrzl + bo2);
      az[j] = __builtin_amdgcn_mfma_f32_16x16x32_bf16(ah, bh2, az[j], 0, 0, 0);
      az[j] = __builtin_amdgcn_mfma_f32_16x16x32_bf16(ah, bl2, az[j], 0, 0, 0);
      az[j] = __builtin_amdgcn_mfma_f32_16x16x32_bf16(al, bh2, az[j], 0, 0, 0);
    }
  }
  for(int kt = 0; kt < 8; ++kt){
    int koff = kt*32;
    bf16x8 ah = *(const bf16x8*)(fsh + arow + koff);
    bf16x8 al = *(const bf16x8*)(fsl + arow + koff);
    bf16x8 gh = *(const bf16x8*)(hhi + arow + koff);
    bf16x8 gl = *(const bf16x8*)(hlo + arow + koff);
    #pragma unroll
    for(int j = 0; j < 4; ++j){
      size_t bo = ((size_t)(kt*16 + w*4 + j)*64 + l)*8;
      bf16x8 bh = *(const bf16x8*)(winh + bo);
      bf16x8 bl = *(const bf16x8*)(winl + bo);
      aa[j] = __builtin_amdgcn_mfma_f32_16x16x32_bf16(ah, bh, aa[j], 0, 0, 0);
      aa[j] = __builtin_amdgcn_mfma_f32_16x16x32_bf16(ah, bl, aa[j], 0, 0, 0);
      aa[j] = __builtin_amdgcn_mfma_f32_16x16x32_bf16(al, bh, aa[j], 0, 0, 0);
      bf16x8 ch = *(const bf16x8*)(whnh + bo);
      bf16x8 cl2 = *(const bf16x8*)(whnl + bo);
      ab[j] = __builtin_amdgcn_mfma_f32_16x16x32_bf16(gh, ch, ab[j], 0, 0, 0);
      ab[j] = __builtin_amdgcn_mfma_f32_16x16x32_bf16(gh, cl2, ab[j], 0, 0, 0);
      ab[j] = __builtin_amdgcn_mfma_f32_16x16x32_bf16(gl, ch, ab[j], 0, 0, 0);
    }
  }
  int cl = l & 15, rq = l >> 4;
  float hnew[4][4];
  float s1[4] = {0.f,0.f,0.f,0.f}, s2[4] = {0.f,0.f,0.f,0.f};
  #pragma unroll
  for(int j = 0; j < 4; ++j){
    int col = w*64 + j*16 + cl;
    float br = bih[col] + bhh[col];
    float bz = bih[256+col] + bhh[256+col];
    float bi = bih[512+col];
    float bh2 = bhh[512+col];
    #pragma unroll
    for(int q = 0; q < 4; ++q){
      int row = m0 + rq*4 + q;
      float rs = ar[j][q] + br;
      float zs = az[j][q] + bz;
      float in_ = aa[j][q] + bi;
      float hn  = ab[j][q] + bh2;
      float h   = hidden[(size_t)row*256 + col];
      float r = 1.f/(1.f + expf(-rs));
      float z = 1.f/(1.f + expf(-zs));
      float nv = tanhf(in_ + r*hn);
      float hv = (1.f - z)*nv + z*h;
      hnew[j][q] = hv;
      hout[(size_t)row*256 + col] = hv;
      s1[q] += hv; s2[q] += hv*hv;
    }
  }
  #pragma unroll
  for(int q = 0; q < 4; ++q){
    for(int off = 1; off < 16; off <<= 1){
      s1[q] += __shfl_xor(s1[q], off);
      s2[q] += __shfl_xor(s2[q], off);
    }
  }
  if(cl == 0){
    #pragma unroll
    for(int q = 0; q < 4; ++q){
      s_s1[w*16 + rq*4 + q] = s1[q];
      s_s2[w*16 + rq*4 + q] = s2[q];
    }
  }
  __syncthreads();
  if(threadIdx.x < 16){
    int rr = threadIdx.x;
    float t1 = s_s1[rr] + s_s1[16+rr] + s_s1[32+rr] + s_s1[48+rr];
    float t2 = s_s2[rr] + s_s2[16+rr] + s_s2[32+rr] + s_s2[48+rr];
    float mu = t1 * (1.f/256.f);
    float var = t2 * (1.f/256.f) - mu*mu;
    s_mu[rr] = mu;
    s_rs[rr] = rsqrtf(var + 1e-5f);
  }
  __syncthreads();
  #pragma unroll
  for(int j = 0; j < 4; ++j){
    int col = w*64 + j*16 + cl;
    float g = lng[col], bb = lnb[col];
    #pragma unroll
    for(int q = 0; q < 4; ++q){
      int rloc = rq*4 + q;
      float bel = (hnew[j][q] - s_mu[rloc]) * s_rs[rloc] * g + bb;
      u16 hb = f2bf(bel);
      size_t o = (size_t)(m0 + rloc)*256 + col;
      belh[o] = hb; bell[o] = f2bf(bel - bf2f(hb));
    }
  }
}

// ---------- W3 head + project_power (16 rows/block, 16 lanes/row) ----------
__global__ __launch_bounds__(256) void k_head(
    const float* __restrict__ x2, const float* __restrict__ W3,
    const float* __restrict__ b3, float* __restrict__ act)
{
  __shared__ float sW[2048];
  int t = threadIdx.x;
  for(int i = t; i < 2048; i += 256) sW[i] = W3[i];
  __syncthreads();
  int rl = t >> 4, j = t & 15;
  int b = blockIdx.x*16 + rl;
  const float* xr = x2 + (size_t)b*128;
  float raw = b3[j];
  #pragma unroll 8
  for(int k4 = 0; k4 < 32; ++k4){
    float4 v = *(const float4*)(xr + k4*4);
    raw += v.x*sW[(k4*4+0)*16 + j] + v.y*sW[(k4*4+1)*16 + j]
         + v.z*sW[(k4*4+2)*16 + j] + v.w*sW[(k4*4+3)*16 + j];
  }
  float c0 = fminf(fmaxf(raw, 0.f), 0.5f);
  float tot = c0;
  for(int off = 8; off; off >>= 1) tot += __shfl_xor(tot, off);
  float mx = raw;
  for(int off = 8; off; off >>= 1) mx = fmaxf(mx, __shfl_xor(mx, off));
  bool feas = (tot <= 1.0f);
  float lo = 0.f, hi = fmaxf(mx, 0.f);
  for(int it = 0; it < 60; ++it){
    float mid = 0.5f*(lo + hi);
    float s = fminf(fmaxf(raw - mid, 0.f), 0.5f);
    for(int off = 8; off; off >>= 1) s += __shfl_xor(s, off);
    bool over = s > 1.0f;
    lo = over ? mid : lo;
    hi = over ? hi : mid;
  }
  float muv = feas ? 0.f : hi;
  act[(size_t)b*16 + j] = fminf(fmaxf(raw - muv, 0.f), 0.5f);
}

// ---------- workspace layout (bytes) ----------
#define OFF_FLAG   0u
#define OFF_WAS    256u
#define OFF_WAD    2304u
#define OFF_WBIG   4352u
#define OFF_FFH    692480u
#define OFF_FFL    1036544u
#define OFF_WRZH   1380608u
#define OFF_WRZL   1904896u
#define OFF_WINH   2429184u
#define OFF_WINL   2560256u
#define OFF_WHNH   2691328u
#define OFF_WHNL   2822400u
#define OFF_F1H    2953472u
#define OFF_F1L    3084544u
#define OFF_F2H    3215616u
#define OFF_F2L    3281152u
#define OFF_XCATH  3346688u
#define OFF_XCATL  14356736u
#define OFF_FSH    25366784u
#define OFF_FSL    29561088u
#define OFF_HHI    33755392u
#define OFF_HLO    37949696u
#define OFF_X1H    42144000u
#define OFF_X1L    46338304u
#define OFF_X2     50532608u
#define OFF_BELH   54726912u
#define OFF_BELL   58921216u
// total: 63,115,520 bytes

extern "C" void kernel_launch(void* const* d_in, const int* in_sizes, int n_in,
                              void* d_out, int out_size, void* d_ws, size_t ws_size,
                              hipStream_t stream){
  const float* node   = (const float*)d_in[0];
  const float* nbr    = (const float*)d_in[1];
  const void*  mask   = d_in[2];
  const float* hidden = (const float*)d_in[3];
  const float* Wg     = (const float*)d_in[4];
  const float* ag     = (const float*)d_in[5];
  const float* fW     = (const float*)d_in[6];
  const float* fb     = (const float*)d_in[7];
  const float* Wih    = (const float*)d_in[8];
  const float* bih    = (const float*)d_in[9];
  const float* Whh    = (const float*)d_in[10];
  const float* bhh    = (const float*)d_in[11];
  const float* lng    = (const float*)d_in[12];
  const float* lnb    = (const float*)d_in[13];
  const float* W1     = (const float*)d_in[14];
  const float* b1     = (const float*)d_in[15];
  const float* W2     = (const float*)d_in[16];
  const float* b2     = (const float*)d_in[17];
  const float* W3     = (const float*)d_in[18];
  const float* b3     = (const float*)d_in[19];
  char* ws = (char*)d_ws;
  float* out = (float*)d_out;

  int*   flag = (int*)  (ws + OFF_FLAG);
  float* was  = (float*)(ws + OFF_WAS);
  float* wad  = (float*)(ws + OFF_WAD);
  float* wbig = (float*)(ws + OFF_WBIG);
  u16* ffh  = (u16*)(ws + OFF_FFH);   u16* ffl  = (u16*)(ws + OFF_FFL);
  u16* wrzh = (u16*)(ws + OFF_WRZH);  u16* wrzl = (u16*)(ws + OFF_WRZL);
  u16* winh = (u16*)(ws + OFF_WINH);  u16* winl = (u16*)(ws + OFF_WINL);
  u16* whnh = (u16*)(ws + OFF_WHNH);  u16* whnl = (u16*)(ws + OFF_WHNL);
  u16* f1h  = (u16*)(ws + OFF_F1H);   u16* f1l  = (u16*)(ws + OFF_F1L);
  u16* f2h  = (u16*)(ws + OFF_F2H);   u16* f2l  = (u16*)(ws + OFF_F2L);
  u16* xh   = (u16*)(ws + OFF_XCATH); u16* xl   = (u16*)(ws + OFF_XCATL);
  u16* fsh  = (u16*)(ws + OFF_FSH);   u16* fsl  = (u16*)(ws + OFF_FSL);
  u16* hhi  = (u16*)(ws + OFF_HHI);   u16* hlo  = (u16*)(ws + OFF_HLO);
  u16* x1h  = (u16*)(ws + OFF_X1H);   u16* x1l  = (u16*)(ws + OFF_X1L);
  float* x2 = (float*)(ws + OFF_X2);
  u16* beh  = (u16*)(ws + OFF_BELH);  u16* bel  = (u16*)(ws + OFF_BELL);

  // preprocessing (constant folding of weights)
  k_probe<<<1, 64, 0, stream>>>((const unsigned char*)mask, flag);
  k_wa<<<1, 512, 0, stream>>>(Wg, ag, was, wad);
  k_wbig<<<672, 256, 0, stream>>>(fW, Wg, wbig);
  k_frag<<<21*16, 64, 0, stream>>>(wbig, 256, 0, 16, ffh, ffl);
  // rz weights: [Wih_rz (kt 0..7); Whh_rz (kt 8..15)], NT=32
  k_frag<<<8*32, 64, 0, stream>>>(Wih, 768, 0, 32, wrzh, wrzl);
  k_frag<<<8*32, 64, 0, stream>>>(Whh, 768, 0, 32, wrzh + 131072, wrzl + 131072);
  k_frag<<<8*16, 64, 0, stream>>>(Wih, 768, 512, 16, winh, winl);
  k_frag<<<8*16, 64, 0, stream>>>(Whh, 768, 512, 16, whnh, whnl);
  k_frag<<<8*16, 64, 0, stream>>>(W1, 256, 0, 16, f1h, f1l);
  k_frag<<<8*8,  64, 0, stream>>>(W2, 128, 0, 8, f2h, f2l);
  k_split<<<1024, 256, 0, stream>>>(hidden, hhi, hlo, 262144);

  // GAT -> x_cat (hi/lo)
  k_gat<<<8192, 256, 0, stream>>>(nbr, node, mask, flag, was, wad, xh, xl);

  // fused = relu(x_cat @ Wbig + fb): rows 32/block, col-split 2
  k_gemm3<21,16,2,2,0><<<dim3(256,2), 256, 0, stream>>>(xh, xl, ffh, ffl, fb, nullptr, fsh, fsl);
  // GRU + LN fused
  k_gru<<<512, 256, 0, stream>>>(fsh, fsl, hhi, hlo, wrzh, wrzl, winh, winl,
                                 whnh, whnl, bih, bhh, hidden, lng, lnb,
                                 out + ACT_TOT, beh, bel);
  // MLP
  k_gemm3<8,16,2,2,0><<<dim3(256,2), 256, 0, stream>>>(beh, bel, f1h, f1l, b1, nullptr, x1h, x1l);
  k_gemm3<8,8,1,2,2><<<dim3(256,2), 256, 0, stream>>>(x1h, x1l, f2h, f2l, b2, x2, nullptr, nullptr);
  // head + projection
  k_head<<<512, 256, 0, stream>>>(x2, W3, b3, out);
}

// Round 5
// 225.764 us; speedup vs baseline: 1.6307x; 1.1669x over previous
//
#include <hip/hip_runtime.h>
#include <hip/hip_bf16.h>

// ActorNetwork fused pipeline for MI355X — round 5 (round 4 + fixed ws layout).
// GAT collapsed via wa = W_gat @ a and Wbig = [fusion_W[0:129]; W_gat x fusion_W[129:]].
// All preprocessing merged into 2 kernels. GEMMs ROWF=4 (B L2-demand < 56 B/cyc/CU).
// GRU v2: 32 rows/block, 8 waves. W2+head+project fused (x2 in LDS).

typedef unsigned short u16;
typedef unsigned int   u32;
typedef __attribute__((ext_vector_type(8))) short bf16x8;
typedef __attribute__((ext_vector_type(4))) float f32x4;

#define KFUSE  672   // 641 padded to 21*32
#define ACT_TOT (8192*16)

__device__ __forceinline__ u16 f2bf(float x){
  u32 u = __float_as_uint(x);
  u += 0x7fffu + ((u >> 16) & 1u);   // round-to-nearest-even
  return (u16)(u >> 16);
}
__device__ __forceinline__ float bf2f(u16 h){ return __uint_as_float(((u32)h) << 16); }

// generic: one MFMA B-fragment (64 lanes) from fp32 src
__device__ __forceinline__ void frag_one(const float* __restrict__ src, int ld, int col0,
                                         int NT, u16* __restrict__ dhi, u16* __restrict__ dlo,
                                         int f, int fsrc, int l){
  int kt = fsrc / NT, nt = fsrc % NT;
  int kbase = kt*32 + (l >> 4)*8, n = col0 + nt*16 + (l & 15);
  size_t o = ((size_t)f*64 + l)*8;
  #pragma unroll
  for(int i = 0; i < 8; ++i){
    float w = src[(size_t)(kbase + i)*ld + n];
    u16 h = f2bf(w);
    dhi[o + i] = h;
    dlo[o + i] = f2bf(w - bf2f(h));
  }
}

// ---------- prep kernel 1: probe + wa + wbig + direct weight frags + h split ----------
#define B_WBIG0 1
#define B_WRZA  673
#define B_WRZB  737
#define B_WIN   801
#define B_WHN   833
#define B_F1    865
#define B_F2    897
#define B_SPLIT 913
// grid = 1937
__global__ __launch_bounds__(256) void k_prep1(
    const unsigned char* __restrict__ maskb, int* __restrict__ flag,
    const float* __restrict__ Wg, const float* __restrict__ ag,
    float* __restrict__ was, float* __restrict__ wad,
    const float* __restrict__ fW, float* __restrict__ wbig,
    const float* __restrict__ Wih, const float* __restrict__ Whh,
    const float* __restrict__ W1, const float* __restrict__ W2,
    u16* __restrict__ wrzh, u16* __restrict__ wrzl,
    u16* __restrict__ winh, u16* __restrict__ winl,
    u16* __restrict__ whnh, u16* __restrict__ whnl,
    u16* __restrict__ f1h, u16* __restrict__ f1l,
    u16* __restrict__ f2h, u16* __restrict__ f2l,
    const float* __restrict__ hidden, u16* __restrict__ acath, u16* __restrict__ acatl)
{
  int bx = blockIdx.x, t = threadIdx.x;
  if(bx == 0){
    if(t == 0){
      int s = 0;
      for(int i = 1; i < 256; i += 4) s += maskb[i];
      *flag = (s == 0) ? 1 : 0;
    }
    #pragma unroll
    for(int v = 0; v < 2; ++v){
      int idx = v*256 + t, k = idx & 127, h = idx >> 7;
      float s = 0.f, d = 0.f;
      for(int f = 0; f < 64; ++f){
        float w = Wg[k*256 + h*64 + f];
        s += w * ag[h*128 + f];
        d += w * ag[h*128 + 64 + f];
      }
      was[k*4 + h] = s; wad[k*4 + h] = d;
    }
  } else if(bx < B_WRZA){
    int r = bx - B_WBIG0, j = t;
    float v;
    if(r < 129) v = fW[r*256 + j];
    else if(r < 641){
      int h = (r - 129) >> 7, kk = (r - 129) & 127;
      float s = 0.f;
      for(int f = 0; f < 64; ++f) s += Wg[kk*256 + h*64 + f] * fW[(129 + h*64 + f)*256 + j];
      v = s;
    } else v = 0.f;
    wbig[r*256 + j] = v;
  } else if(bx < B_SPLIT){
    int sub = t >> 6, l = t & 63;
    if(bx < B_WRZB){        // Wih rz: frags 0..255, NT=32
      int f = (bx - B_WRZA)*4 + sub;
      frag_one(Wih, 768, 0, 32, wrzh, wrzl, f, f, l);
    } else if(bx < B_WIN){  // Whh rz: frags 256..511 (src frag 0..255)
      int fl = (bx - B_WRZB)*4 + sub;
      frag_one(Whh, 768, 0, 32, wrzh, wrzl, 256 + fl, fl, l);
    } else if(bx < B_WHN){  // Wih n: 128 frags NT=16 col0 512
      int f = (bx - B_WIN)*4 + sub;
      frag_one(Wih, 768, 512, 16, winh, winl, f, f, l);
    } else if(bx < B_F1){   // Whh n
      int f = (bx - B_WHN)*4 + sub;
      frag_one(Whh, 768, 512, 16, whnh, whnl, f, f, l);
    } else if(bx < B_F2){   // W1: 128 frags NT=16
      int f = (bx - B_F1)*4 + sub;
      frag_one(W1, 256, 0, 16, f1h, f1l, f, f, l);
    } else {                // W2: 64 frags NT=8
      int f = (bx - B_F2)*4 + sub;
      frag_one(W2, 128, 0, 8, f2h, f2l, f, f, l);
    }
  } else {
    // h split -> ACAT cols 256..511 (row stride 512)
    int i = (bx - B_SPLIT)*256 + t;     // 0..262143, 8 f32 each
    int idx8 = i*8, row = idx8 >> 8, col = idx8 & 255;
    const float4* p = (const float4*)(hidden + (size_t)idx8);
    float4 v0 = p[0], v1 = p[1];
    float vv[8] = {v0.x,v0.y,v0.z,v0.w,v1.x,v1.y,v1.z,v1.w};
    u16 h8[8], l8[8];
    #pragma unroll
    for(int q = 0; q < 8; ++q){ u16 h = f2bf(vv[q]); h8[q] = h; l8[q] = f2bf(vv[q] - bf2f(h)); }
    uint4 uh = { (u32)h8[0] | ((u32)h8[1]<<16), (u32)h8[2] | ((u32)h8[3]<<16),
                 (u32)h8[4] | ((u32)h8[5]<<16), (u32)h8[6] | ((u32)h8[7]<<16) };
    uint4 ul = { (u32)l8[0] | ((u32)l8[1]<<16), (u32)l8[2] | ((u32)l8[3]<<16),
                 (u32)l8[4] | ((u32)l8[5]<<16), (u32)l8[6] | ((u32)l8[7]<<16) };
    size_t off = (size_t)row*512 + 256 + col;
    *(uint4*)(acath + off) = uh;
    *(uint4*)(acatl + off) = ul;
  }
}

// ---------- prep kernel 2: wbig frags (depends on prep1) ----------
__global__ __launch_bounds__(256) void k_prep2(
    const float* __restrict__ wbig, u16* __restrict__ ffh, u16* __restrict__ ffl)
{
  int f = blockIdx.x*4 + (threadIdx.x >> 6), l = threadIdx.x & 63;   // 84 blocks -> 336 frags
  frag_one(wbig, 256, 0, 16, ffh, ffl, f, f, l);
}

// ---------- GAT kernel: one block per batch row, coalesced load, 39.9 KB LDS ----------
__global__ __launch_bounds__(256) void k_gat(
    const float* __restrict__ nbg, const float* __restrict__ node,
    const void* __restrict__ maskp, const int* __restrict__ flagp,
    const float* __restrict__ was, const float* __restrict__ wad,
    u16* __restrict__ xhi, u16* __restrict__ xlo)
{
  __shared__ float s_nb[8192];     // [n][ch^(n&31)] float4 chunks
  __shared__ float s_wad[512];
  __shared__ float s_ep[1024];     // ed partials [c][n][h]
  __shared__ float s_alpha[256];   // [h][n]
  int b = blockIdx.x, t = threadIdx.x;
  const float* nb = nbg + (size_t)b*8192;
  const int isint = *flagp;

  s_wad[t] = wad[t]; s_wad[t+256] = wad[t+256];

  #pragma unroll
  for(int q = 0; q < 8; ++q){
    int f = q*256 + t;
    int n = f >> 5, ch = f & 31;
    float4 v = *(const float4*)(nb + f*4);
    *(float4*)(s_nb + (n*32 + (ch ^ (n & 31)))*4) = v;
  }

  if(t < 129){
    float v;
    if(t < 2){
      float ph = node[(size_t)b*128] * (6.2831853071795864769f / 24.0f);
      v = (t == 0) ? sinf(ph) : cosf(ph);
    } else v = node[(size_t)b*128 + (t-1)];
    u16 h = f2bf(v);
    size_t o = (size_t)b*KFUSE + t;
    xhi[o] = h; xlo[o] = f2bf(v - bf2f(h));
  } else if(t < 160){
    size_t o = (size_t)b*KFUSE + 641 + (t - 129);
    xhi[o] = 0; xlo[o] = 0;
  }
  __syncthreads();

  {
    int n = t & 63, c = t >> 6;
    float adx = 0.f, ady = 0.f, adz = 0.f, adw = 0.f;
    #pragma unroll
    for(int q = 0; q < 8; ++q){
      int ch = c*8 + q;
      float4 v = *(const float4*)(s_nb + (n*32 + (ch ^ (n & 31)))*4);
      float vv[4] = {v.x, v.y, v.z, v.w};
      #pragma unroll
      for(int i2 = 0; i2 < 4; ++i2){
        int k = ch*4 + i2;
        float4 wd = *(const float4*)(s_wad + k*4);
        adx += vv[i2]*wd.x; ady += vv[i2]*wd.y; adz += vv[i2]*wd.z; adw += vv[i2]*wd.w;
      }
    }
    float4 ad = {adx, ady, adz, adw};
    *(float4*)(s_ep + (c*64 + n)*4) = ad;
  }
  __syncthreads();

  {
    int n2 = t & 63, h2 = t >> 6;
    float es = 0.f;
    #pragma unroll
    for(int ii = 0; ii < 2; ++ii){
      int k = n2*2 + ii;
      float v0 = s_nb[(k >> 2)*4 + (k & 3)];
      es += v0 * was[k*4 + h2];
    }
    for(int off = 32; off; off >>= 1) es += __shfl_xor(es, off);
    float ed = s_ep[n2*4 + h2] + s_ep[(64+n2)*4 + h2]
             + s_ep[(128+n2)*4 + h2] + s_ep[(192+n2)*4 + h2];
    float e = es + ed;
    e = (e > 0.f) ? e : 0.2f*e;
    bool valid;
    if(isint) valid = ((const u32*)maskp)[(size_t)b*64 + n2] != 0u;
    else      valid = ((const unsigned char*)maskp)[(size_t)b*64 + n2] != 0;
    float ev = valid ? e : -1e30f;
    float m = ev;
    for(int off = 32; off; off >>= 1) m = fmaxf(m, __shfl_xor(m, off));
    float p = valid ? expf(ev - m) : 0.f;
    float s = p;
    for(int off = 32; off; off >>= 1) s += __shfl_xor(s, off);
    s_alpha[t] = p / s;   // [h][n]
  }
  __syncthreads();

  {
    int k = t & 127, hp = (t >> 7)*2;
    int ch = k >> 2, sub = k & 3;
    float a0 = 0.f, a1 = 0.f;
    #pragma unroll 4
    for(int nn = 0; nn < 64; ++nn){
      float v = s_nb[(nn*32 + (ch ^ (nn & 31)))*4 + sub];
      a0 += v * s_alpha[hp*64 + nn];
      a1 += v * s_alpha[(hp+1)*64 + nn];
    }
    size_t o0 = (size_t)b*KFUSE + 129 + hp*128 + k;
    u16 h0 = f2bf(a0); xhi[o0] = h0; xlo[o0] = f2bf(a0 - bf2f(h0));
    size_t o1 = o0 + 128;
    u16 h1 = f2bf(a1); xhi[o1] = h1; xlo[o1] = f2bf(a1 - bf2f(h1));
  }
}

// ---------- split-bf16 MFMA GEMM: ROWF row-frags, col-split grid ----------
template<int KT, int NT_TOT, int NPW, int ROWF>
__global__ __launch_bounds__(256) void k_gemm3(
    const u16* __restrict__ xhi, const u16* __restrict__ xlo, int lda,
    const u16* __restrict__ wfhi, const u16* __restrict__ wflo,
    const float* __restrict__ bias,
    u16* __restrict__ ohi, u16* __restrict__ olo, int ost, int ocol)
{
  int l = threadIdx.x & 63, w = threadIdx.x >> 6;
  int m0 = blockIdx.x * (16*ROWF);
  int ntbase = blockIdx.y * (4*NPW) + w*NPW;
  f32x4 acc[NPW][ROWF];
  #pragma unroll
  for(int j = 0; j < NPW; ++j)
    #pragma unroll
    for(int rf = 0; rf < ROWF; ++rf) acc[j][rf] = (f32x4){0.f,0.f,0.f,0.f};
  size_t arow[ROWF];
  #pragma unroll
  for(int rf = 0; rf < ROWF; ++rf)
    arow[rf] = (size_t)(m0 + rf*16 + (l & 15))*lda + (size_t)((l >> 4)*8);
  for(int kt = 0; kt < KT; ++kt){
    bf16x8 ah[ROWF], al[ROWF];
    #pragma unroll
    for(int rf = 0; rf < ROWF; ++rf){
      ah[rf] = *(const bf16x8*)(xhi + arow[rf] + kt*32);
      al[rf] = *(const bf16x8*)(xlo + arow[rf] + kt*32);
    }
    #pragma unroll
    for(int j = 0; j < NPW; ++j){
      size_t bo = ((size_t)(kt*NT_TOT + ntbase + j)*64 + l)*8;
      bf16x8 bh = *(const bf16x8*)(wfhi + bo);
      bf16x8 bl = *(const bf16x8*)(wflo + bo);
      #pragma unroll
      for(int rf = 0; rf < ROWF; ++rf){
        acc[j][rf] = __builtin_amdgcn_mfma_f32_16x16x32_bf16(ah[rf], bh, acc[j][rf], 0, 0, 0);
        acc[j][rf] = __builtin_amdgcn_mfma_f32_16x16x32_bf16(ah[rf], bl, acc[j][rf], 0, 0, 0);
        acc[j][rf] = __builtin_amdgcn_mfma_f32_16x16x32_bf16(al[rf], bh, acc[j][rf], 0, 0, 0);
      }
    }
  }
  #pragma unroll
  for(int j = 0; j < NPW; ++j){
    int col = (ntbase + j)*16 + (l & 15);
    float bv = bias[col];
    #pragma unroll
    for(int rf = 0; rf < ROWF; ++rf){
      int r0 = m0 + rf*16 + (l >> 4)*4;
      #pragma unroll
      for(int q = 0; q < 4; ++q){
        float y = fmaxf(acc[j][rf][q] + bv, 0.f);
        size_t o = (size_t)(r0 + q)*ost + ocol + col;
        u16 h = f2bf(y);
        ohi[o] = h; olo[o] = f2bf(y - bf2f(h));
      }
    }
  }
}

// ---------- fused GRU v2: 512 threads, 32 rows/block, 8 waves x 32 cols ----------
__global__ __launch_bounds__(512) void k_gru(
    const u16* __restrict__ ah_, const u16* __restrict__ al_,
    const u16* __restrict__ wrzh, const u16* __restrict__ wrzl,
    const u16* __restrict__ winh, const u16* __restrict__ winl,
    const u16* __restrict__ whnh, const u16* __restrict__ whnl,
    const float* __restrict__ bih, const float* __restrict__ bhh,
    const float* __restrict__ hidden, const float* __restrict__ lng,
    const float* __restrict__ lnb,
    float* __restrict__ hout, u16* __restrict__ belh, u16* __restrict__ bell)
{
  __shared__ float s_s1[256], s_s2[256];
  __shared__ float s_mu[32], s_rs[32];
  int l = threadIdx.x & 63, w = threadIdx.x >> 6;   // 8 waves
  int m0 = blockIdx.x*32;
  f32x4 ar[2][2], az[2][2], aa[2][2], ab[2][2];
  #pragma unroll
  for(int j = 0; j < 2; ++j)
    #pragma unroll
    for(int rf = 0; rf < 2; ++rf){
      ar[j][rf] = (f32x4){0.f,0.f,0.f,0.f}; az[j][rf] = (f32x4){0.f,0.f,0.f,0.f};
      aa[j][rf] = (f32x4){0.f,0.f,0.f,0.f}; ab[j][rf] = (f32x4){0.f,0.f,0.f,0.f};
    }
  size_t arow[2];
  #pragma unroll
  for(int rf = 0; rf < 2; ++rf)
    arow[rf] = (size_t)(m0 + rf*16 + (l & 15))*512 + (size_t)((l >> 4)*8);
  for(int kt = 0; kt < 16; ++kt){
    bf16x8 ah[2], al[2];
    #pragma unroll
    for(int rf = 0; rf < 2; ++rf){
      ah[rf] = *(const bf16x8*)(ah_ + arow[rf] + kt*32);
      al[rf] = *(const bf16x8*)(al_ + arow[rf] + kt*32);
    }
    #pragma unroll
    for(int j = 0; j < 2; ++j){
      int nt = w*2 + j;
      int fr = kt*32 + nt;
      size_t bo = ((size_t)fr*64 + l)*8;
      bf16x8 bh = *(const bf16x8*)(wrzh + bo);
      bf16x8 bl = *(const bf16x8*)(wrzl + bo);
      size_t bo2 = bo + (size_t)16*64*8;    // z-frags at nt+16
      bf16x8 bh2 = *(const bf16x8*)(wrzh + bo2);
      bf16x8 bl2 = *(const bf16x8*)(wrzl + bo2);
      #pragma unroll
      for(int rf = 0; rf < 2; ++rf){
        ar[j][rf] = __builtin_amdgcn_mfma_f32_16x16x32_bf16(ah[rf], bh, ar[j][rf], 0, 0, 0);
        ar[j][rf] = __builtin_amdgcn_mfma_f32_16x16x32_bf16(ah[rf], bl, ar[j][rf], 0, 0, 0);
        ar[j][rf] = __builtin_amdgcn_mfma_f32_16x16x32_bf16(al[rf], bh, ar[j][rf], 0, 0, 0);
        az[j][rf] = __builtin_amdgcn_mfma_f32_16x16x32_bf16(ah[rf], bh2, az[j][rf], 0, 0, 0);
        az[j][rf] = __builtin_amdgcn_mfma_f32_16x16x32_bf16(ah[rf], bl2, az[j][rf], 0, 0, 0);
        az[j][rf] = __builtin_amdgcn_mfma_f32_16x16x32_bf16(al[rf], bh2, az[j][rf], 0, 0, 0);
      }
    }
  }
  for(int kt = 0; kt < 8; ++kt){
    bf16x8 fh[2], fl2[2], gh[2], gl[2];
    #pragma unroll
    for(int rf = 0; rf < 2; ++rf){
      fh[rf]  = *(const bf16x8*)(ah_ + arow[rf] + kt*32);
      fl2[rf] = *(const bf16x8*)(al_ + arow[rf] + kt*32);
      gh[rf]  = *(const bf16x8*)(ah_ + arow[rf] + 256 + kt*32);
      gl[rf]  = *(const bf16x8*)(al_ + arow[rf] + 256 + kt*32);
    }
    #pragma unroll
    for(int j = 0; j < 2; ++j){
      int nt = w*2 + j;
      size_t bo = ((size_t)(kt*16 + nt)*64 + l)*8;
      bf16x8 bh = *(const bf16x8*)(winh + bo);
      bf16x8 bl = *(const bf16x8*)(winl + bo);
      bf16x8 ch = *(const bf16x8*)(whnh + bo);
      bf16x8 cl2 = *(const bf16x8*)(whnl + bo);
      #pragma unroll
      for(int rf = 0; rf < 2; ++rf){
        aa[j][rf] = __builtin_amdgcn_mfma_f32_16x16x32_bf16(fh[rf], bh, aa[j][rf], 0, 0, 0);
        aa[j][rf] = __builtin_amdgcn_mfma_f32_16x16x32_bf16(fh[rf], bl, aa[j][rf], 0, 0, 0);
        aa[j][rf] = __builtin_amdgcn_mfma_f32_16x16x32_bf16(fl2[rf], bh, aa[j][rf], 0, 0, 0);
        ab[j][rf] = __builtin_amdgcn_mfma_f32_16x16x32_bf16(gh[rf], ch, ab[j][rf], 0, 0, 0);
        ab[j][rf] = __builtin_amdgcn_mfma_f32_16x16x32_bf16(gh[rf], cl2, ab[j][rf], 0, 0, 0);
        ab[j][rf] = __builtin_amdgcn_mfma_f32_16x16x32_bf16(gl[rf], ch, ab[j][rf], 0, 0, 0);
      }
    }
  }
  int cl = l & 15, rq = l >> 4;
  float hnew[2][2][4];
  float s1p[2][4], s2p[2][4];
  #pragma unroll
  for(int rf = 0; rf < 2; ++rf)
    #pragma unroll
    for(int q = 0; q < 4; ++q){ s1p[rf][q] = 0.f; s2p[rf][q] = 0.f; }
  #pragma unroll
  for(int j = 0; j < 2; ++j){
    int col = w*32 + j*16 + cl;
    float br = bih[col] + bhh[col];
    float bz = bih[256+col] + bhh[256+col];
    float bi = bih[512+col];
    float bh2 = bhh[512+col];
    #pragma unroll
    for(int rf = 0; rf < 2; ++rf){
      #pragma unroll
      for(int q = 0; q < 4; ++q){
        int row = m0 + rf*16 + rq*4 + q;
        float rs = ar[j][rf][q] + br;
        float zs = az[j][rf][q] + bz;
        float in_ = aa[j][rf][q] + bi;
        float hn  = ab[j][rf][q] + bh2;
        float h   = hidden[(size_t)row*256 + col];
        float r = 1.f/(1.f + expf(-rs));
        float z = 1.f/(1.f + expf(-zs));
        float nv = tanhf(in_ + r*hn);
        float hv = (1.f - z)*nv + z*h;
        hnew[j][rf][q] = hv;
        hout[(size_t)row*256 + col] = hv;
        s1p[rf][q] += hv; s2p[rf][q] += hv*hv;
      }
    }
  }
  #pragma unroll
  for(int rf = 0; rf < 2; ++rf)
    #pragma unroll
    for(int q = 0; q < 4; ++q){
      float a = s1p[rf][q], b2 = s2p[rf][q];
      for(int off = 1; off < 16; off <<= 1){
        a += __shfl_xor(a, off); b2 += __shfl_xor(b2, off);
      }
      if(cl == 0){
        int rloc = rf*16 + rq*4 + q;
        s_s1[w*32 + rloc] = a; s_s2[w*32 + rloc] = b2;
      }
    }
  __syncthreads();
  if(threadIdx.x < 32){
    int rloc = threadIdx.x;
    float t1 = 0.f, t2 = 0.f;
    #pragma unroll
    for(int ww = 0; ww < 8; ++ww){ t1 += s_s1[ww*32 + rloc]; t2 += s_s2[ww*32 + rloc]; }
    float mu = t1 * (1.f/256.f);
    float var = t2 * (1.f/256.f) - mu*mu;
    s_mu[rloc] = mu; s_rs[rloc] = rsqrtf(var + 1e-5f);
  }
  __syncthreads();
  #pragma unroll
  for(int j = 0; j < 2; ++j){
    int col = w*32 + j*16 + cl;
    float g = lng[col], bb = lnb[col];
    #pragma unroll
    for(int rf = 0; rf < 2; ++rf){
      #pragma unroll
      for(int q = 0; q < 4; ++q){
        int rloc = rf*16 + rq*4 + q;
        float bel = (hnew[j][rf][q] - s_mu[rloc]) * s_rs[rloc] * g + bb;
        u16 hb = f2bf(bel);
        size_t o = (size_t)(m0 + rloc)*256 + col;
        belh[o] = hb; bell[o] = f2bf(bel - bf2f(hb));
      }
    }
  }
}

// ---------- fused W2 GEMM + W3 head + project_power: 64 rows/block ----------
__global__ __launch_bounds__(256) void k_w2head(
    const u16* __restrict__ xhi, const u16* __restrict__ xlo,
    const u16* __restrict__ wfhi, const u16* __restrict__ wflo,
    const float* __restrict__ b2, const float* __restrict__ W3,
    const float* __restrict__ b3, float* __restrict__ act)
{
  __shared__ float sx2[64*128];
  __shared__ float sW3[2048];
  int t = threadIdx.x, l = t & 63, w = t >> 6;
  int m0 = blockIdx.x*64;
  for(int i = t; i < 2048; i += 256) sW3[i] = W3[i];
  f32x4 acc[2][4];
  #pragma unroll
  for(int j = 0; j < 2; ++j)
    #pragma unroll
    for(int rf = 0; rf < 4; ++rf) acc[j][rf] = (f32x4){0.f,0.f,0.f,0.f};
  size_t arow[4];
  #pragma unroll
  for(int rf = 0; rf < 4; ++rf)
    arow[rf] = (size_t)(m0 + rf*16 + (l & 15))*256 + (size_t)((l >> 4)*8);
  for(int kt = 0; kt < 8; ++kt){
    bf16x8 ah[4], al[4];
    #pragma unroll
    for(int rf = 0; rf < 4; ++rf){
      ah[rf] = *(const bf16x8*)(xhi + arow[rf] + kt*32);
      al[rf] = *(const bf16x8*)(xlo + arow[rf] + kt*32);
    }
    #pragma unroll
    for(int j = 0; j < 2; ++j){
      size_t bo = ((size_t)(kt*8 + w*2 + j)*64 + l)*8;
      bf16x8 bh = *(const bf16x8*)(wfhi + bo);
      bf16x8 bl = *(const bf16x8*)(wflo + bo);
      #pragma unroll
      for(int rf = 0; rf < 4; ++rf){
        acc[j][rf] = __builtin_amdgcn_mfma_f32_16x16x32_bf16(ah[rf], bh, acc[j][rf], 0, 0, 0);
        acc[j][rf] = __builtin_amdgcn_mfma_f32_16x16x32_bf16(ah[rf], bl, acc[j][rf], 0, 0, 0);
        acc[j][rf] = __builtin_amdgcn_mfma_f32_16x16x32_bf16(al[rf], bh, acc[j][rf], 0, 0, 0);
      }
    }
  }
  int cl = l & 15, rq = l >> 4;
  #pragma unroll
  for(int j = 0; j < 2; ++j){
    int col = (w*2 + j)*16 + cl;
    float bv = b2[col];
    #pragma unroll
    for(int rf = 0; rf < 4; ++rf){
      #pragma unroll
      for(int q = 0; q < 4; ++q){
        int rloc = rf*16 + rq*4 + q;
        sx2[rloc*128 + col] = fmaxf(acc[j][rf][q] + bv, 0.f);
      }
    }
  }
  __syncthreads();
  int j = t & 15, rl = t >> 4;
  #pragma unroll
  for(int rr = 0; rr < 4; ++rr){
    int rloc = rr*16 + rl;
    const float* xr = sx2 + rloc*128;
    float raw = b3[j];
    #pragma unroll 8
    for(int k4 = 0; k4 < 32; ++k4){
      float4 v = *(const float4*)(xr + k4*4);
      raw += v.x*sW3[(k4*4+0)*16 + j] + v.y*sW3[(k4*4+1)*16 + j]
           + v.z*sW3[(k4*4+2)*16 + j] + v.w*sW3[(k4*4+3)*16 + j];
    }
    float c0 = fminf(fmaxf(raw, 0.f), 0.5f);
    float tot = c0;
    for(int off = 8; off; off >>= 1) tot += __shfl_xor(tot, off);
    float mx = raw;
    for(int off = 8; off; off >>= 1) mx = fmaxf(mx, __shfl_xor(mx, off));
    bool feas = (tot <= 1.0f);
    float lo = 0.f, hi = fmaxf(mx, 0.f);
    for(int it = 0; it < 60; ++it){
      float mid = 0.5f*(lo + hi);
      float s = fminf(fmaxf(raw - mid, 0.f), 0.5f);
      for(int off = 8; off; off >>= 1) s += __shfl_xor(s, off);
      bool over = s > 1.0f;
      lo = over ? mid : lo;
      hi = over ? hi : mid;
    }
    float muv = feas ? 0.f : hi;
    act[(size_t)(m0 + rloc)*16 + j] = fminf(fmaxf(raw - muv, 0.f), 0.5f);
  }
}

// ---------- workspace layout (bytes) — FIXED sizes ----------
#define OFF_FLAG   0u
#define OFF_WAS    4096u
#define OFF_WAD    8192u
#define OFF_WBIG   12288u        // 672*256*4 = 688128
#define OFF_FFH    700416u       // 336 frags * 1024 = 344064
#define OFF_FFL    1044480u
#define OFF_WRZH   1388544u      // 512 frags * 1024 = 524288
#define OFF_WRZL   1912832u
#define OFF_WINH   2437120u      // 128 frags * 1024 = 131072
#define OFF_WINL   2568192u
#define OFF_WHNH   2699264u
#define OFF_WHNL   2830336u
#define OFF_F1H    2961408u      // 128 frags
#define OFF_F1L    3092480u
#define OFF_F2H    3223552u      // 64 frags * 1024 = 65536
#define OFF_F2L    3289088u
#define OFF_XCATH  3354624u      // 8192*672*2 = 11010048
#define OFF_XCATL  14364672u
#define OFF_ACATH  25374720u     // 8192*512*2 = 8388608
#define OFF_ACATL  33763328u
#define OFF_BELH   42151936u     // 8192*256*2 = 4194304
#define OFF_BELL   46346240u
#define OFF_X1H    50540544u
#define OFF_X1L    54734848u
// total: 58,929,152 bytes

extern "C" void kernel_launch(void* const* d_in, const int* in_sizes, int n_in,
                              void* d_out, int out_size, void* d_ws, size_t ws_size,
                              hipStream_t stream){
  const float* node   = (const float*)d_in[0];
  const float* nbr    = (const float*)d_in[1];
  const void*  mask   = d_in[2];
  const float* hidden = (const float*)d_in[3];
  const float* Wg     = (const float*)d_in[4];
  const float* ag     = (const float*)d_in[5];
  const float* fW     = (const float*)d_in[6];
  const float* fb     = (const float*)d_in[7];
  const float* Wih    = (const float*)d_in[8];
  const float* bih    = (const float*)d_in[9];
  const float* Whh    = (const float*)d_in[10];
  const float* bhh    = (const float*)d_in[11];
  const float* lng    = (const float*)d_in[12];
  const float* lnb    = (const float*)d_in[13];
  const float* W1     = (const float*)d_in[14];
  const float* b1     = (const float*)d_in[15];
  const float* W2     = (const float*)d_in[16];
  const float* b2     = (const float*)d_in[17];
  const float* W3     = (const float*)d_in[18];
  const float* b3     = (const float*)d_in[19];
  char* ws = (char*)d_ws;
  float* out = (float*)d_out;

  int*   flag = (int*)  (ws + OFF_FLAG);
  float* was  = (float*)(ws + OFF_WAS);
  float* wad  = (float*)(ws + OFF_WAD);
  float* wbig = (float*)(ws + OFF_WBIG);
  u16* ffh  = (u16*)(ws + OFF_FFH);   u16* ffl  = (u16*)(ws + OFF_FFL);
  u16* wrzh = (u16*)(ws + OFF_WRZH);  u16* wrzl = (u16*)(ws + OFF_WRZL);
  u16* winh = (u16*)(ws + OFF_WINH);  u16* winl = (u16*)(ws + OFF_WINL);
  u16* whnh = (u16*)(ws + OFF_WHNH);  u16* whnl = (u16*)(ws + OFF_WHNL);
  u16* f1h  = (u16*)(ws + OFF_F1H);   u16* f1l  = (u16*)(ws + OFF_F1L);
  u16* f2h  = (u16*)(ws + OFF_F2H);   u16* f2l  = (u16*)(ws + OFF_F2L);
  u16* xh   = (u16*)(ws + OFF_XCATH); u16* xl   = (u16*)(ws + OFF_XCATL);
  u16* ach  = (u16*)(ws + OFF_ACATH); u16* acl  = (u16*)(ws + OFF_ACATL);
  u16* beh  = (u16*)(ws + OFF_BELH);  u16* bel  = (u16*)(ws + OFF_BELL);
  u16* x1h  = (u16*)(ws + OFF_X1H);   u16* x1l  = (u16*)(ws + OFF_X1L);

  // preprocessing: 2 launches
  k_prep1<<<1937, 256, 0, stream>>>((const unsigned char*)mask, flag, Wg, ag, was, wad,
                                    fW, wbig, Wih, Whh, W1, W2,
                                    wrzh, wrzl, winh, winl, whnh, whnl,
                                    f1h, f1l, f2h, f2l, hidden, ach, acl);
  k_prep2<<<84, 256, 0, stream>>>(wbig, ffh, ffl);

  // GAT -> x_cat (hi/lo)
  k_gat<<<8192, 256, 0, stream>>>(nbr, node, mask, flag, was, wad, xh, xl);

  // fused = relu(x_cat @ Wbig + fb) -> ACAT cols 0..255 (stride 512)
  k_gemm3<21,16,2,4><<<dim3(128,2), 256, 0, stream>>>(xh, xl, KFUSE, ffh, ffl, fb, ach, acl, 512, 0);
  // GRU + LN fused (reads ACAT = [fs|h])
  k_gru<<<256, 512, 0, stream>>>(ach, acl, wrzh, wrzl, winh, winl, whnh, whnl,
                                 bih, bhh, hidden, lng, lnb, out + ACT_TOT, beh, bel);
  // x1 = relu(bel @ W1 + b1)
  k_gemm3<8,16,2,4><<<dim3(128,2), 256, 0, stream>>>(beh, bel, 256, f1h, f1l, b1, x1h, x1l, 256, 0);
  // x2 = relu(x1 @ W2 + b2) in LDS + head + project
  k_w2head<<<128, 256, 0, stream>>>(x1h, x1l, f2h, f2l, b2, W3, b3, out);
}